// Round 1
// baseline (41882.370 us; speedup 1.0000x reference)
//
#include <hip/hip_runtime.h>
#include <stdint.h>

#define T_STEPS 2048
#define BATCH 32
#define EDIM 512
#define HDIM 512
#define G4H 2048
#define NWG 128
#define KB_TOTAL 16
#define KB_HALF 8

typedef __attribute__((ext_vector_type(8))) short bf16x8;
typedef __attribute__((ext_vector_type(4))) float f32x4;

// ws layout (bytes):
//   [0,512)          flags: 128 u32 (memset 0 per launch)
//   [1024,132096)    hpk[2][32][512] u32 (bf16 hi | lo<<16), double-buffered h
//   [132096, +2MB)   Wpk_hi   (NWG * 16kb * 64lane * 8 shorts)
//   ... Wpk_lo, Upk_hi, Upk_lo (2MB each)
// total ~8.2 MB

__device__ inline unsigned short f2bf(float x){
    unsigned u = __float_as_uint(x);
    unsigned r = (u + 0x7fffu + ((u >> 16) & 1u)) >> 16;
    return (unsigned short)r;
}
__device__ inline float bf2f(unsigned short s){
    return __uint_as_float(((unsigned)s) << 16);
}

__global__ void prep_kernel(const float* __restrict__ W, const float* __restrict__ U,
                            const float* __restrict__ h0,
                            unsigned short* __restrict__ Wh, unsigned short* __restrict__ Wl,
                            unsigned short* __restrict__ Uh, unsigned short* __restrict__ Ul,
                            unsigned int* __restrict__ hpk0){
    int idx = blockIdx.x * blockDim.x + threadIdx.x;
    int stride = gridDim.x * blockDim.x;
    const int total = 2 * EDIM * G4H;  // 2^21
    for (int i = idx; i < total; i += stride){
        int mat = i >> 20;             // 0=W, 1=U
        int r = i & 1048575;
        int k = r >> 11;               // row in [0,512)
        int col = r & 2047;            // gate column
        float v = (mat ? U : W)[(size_t)k * G4H + col];
        unsigned short hi = f2bf(v);
        unsigned short lo = f2bf(v - bf2f(hi));
        int wg = (col & 511) >> 2;     // h-col block
        int hc = col & 3;
        int g  = col >> 9;             // gate 0..3
        int cl = g * 4 + hc;           // col_local 0..15
        int kb = k >> 5;
        int kgrp = (k >> 3) & 3;
        int j = k & 7;
        int l = kgrp * 16 + cl;        // lane
        size_t dst = (size_t)wg * 8192 + (size_t)kb * 512 + (size_t)l * 8 + j;
        if (mat){ Uh[dst] = hi; Ul[dst] = lo; } else { Wh[dst] = hi; Wl[dst] = lo; }
    }
    for (int i = idx; i < BATCH * HDIM; i += stride){
        float v = h0[i];
        unsigned short hi = f2bf(v);
        unsigned short lo = f2bf(v - bf2f(hi));
        hpk0[i] = (unsigned)hi | ((unsigned)lo << 16);
    }
}

__global__ __launch_bounds__(256, 1) void lstm_scan(
        const float* __restrict__ src, const float* __restrict__ bias,
        const float* __restrict__ c0,
        const unsigned short* __restrict__ Wh, const unsigned short* __restrict__ Wl,
        const unsigned short* __restrict__ Uh, const unsigned short* __restrict__ Ul,
        unsigned int* __restrict__ hpk,        // [2][32][512] packed
        unsigned int* __restrict__ flags,      // [128]
        float* __restrict__ out){
    const int tid  = threadIdx.x;
    const int wg   = blockIdx.x;        // 0..127
    const int lane = tid & 63;
    const int w    = tid >> 6;          // wave 0..3
    const int bt   = w & 1;             // batch tile
    const int kh   = w >> 1;            // k half
    const int row  = (lane & 15) + 16 * bt;   // batch index for A frags
    const int kgrp = lane >> 4;

    __shared__ float z_lds[2][BATCH][17];     // [khalf][b][col_local], padded

    // ---- U fragments: register-resident for this wave's k-half ----
    bf16x8 ufh[KB_HALF], ufl[KB_HALF];
    {
        const uint4* ph = reinterpret_cast<const uint4*>(Uh + (size_t)wg * 8192);
        const uint4* pl = reinterpret_cast<const uint4*>(Ul + (size_t)wg * 8192);
        #pragma unroll
        for (int i = 0; i < KB_HALF; i++){
            int kb = kh * KB_HALF + i;
            uint4 a = ph[kb * 64 + lane];
            uint4 b = pl[kb * 64 + lane];
            ufh[i] = *reinterpret_cast<bf16x8*>(&a);
            ufl[i] = *reinterpret_cast<bf16x8*>(&b);
        }
    }

    // ---- gate-thread state (threads 0..127: one cell each) ----
    const int cb  = tid >> 2;      // batch 0..31
    const int chc = tid & 3;       // h-col within wg
    float c_state = 0.f;
    float bias_g[4] = {0.f, 0.f, 0.f, 0.f};
    if (tid < 128){
        c_state = c0[(size_t)cb * HDIM + wg * 4 + chc];
        #pragma unroll
        for (int g = 0; g < 4; g++) bias_g[g] = bias[g * HDIM + wg * 4 + chc];
    }

    f32x4 acc;
    #pragma unroll
    for (int r = 0; r < 4; r++) acc[r] = 0.f;

    // phase A: x_t @ W (independent of recurrence) into acc
    auto phaseA = [&](int t){
        #pragma unroll
        for (int i = 0; i < KB_HALF; i++){
            int kb = kh * KB_HALF + i;
            const float* xp = src + ((size_t)row * T_STEPS + t) * EDIM + kb * 32 + kgrp * 8;
            float xv[8];
            *reinterpret_cast<float4*>(&xv[0]) = *reinterpret_cast<const float4*>(xp);
            *reinterpret_cast<float4*>(&xv[4]) = *reinterpret_cast<const float4*>(xp + 4);
            bf16x8 ah, al;
            #pragma unroll
            for (int j = 0; j < 8; j++){
                unsigned short hi = f2bf(xv[j]);
                ah[j] = (short)hi;
                al[j] = (short)f2bf(xv[j] - bf2f(hi));
            }
            uint4 bh4 = reinterpret_cast<const uint4*>(Wh + (size_t)wg * 8192)[kb * 64 + lane];
            uint4 bl4 = reinterpret_cast<const uint4*>(Wl + (size_t)wg * 8192)[kb * 64 + lane];
            bf16x8 bh = *reinterpret_cast<bf16x8*>(&bh4);
            bf16x8 bl = *reinterpret_cast<bf16x8*>(&bl4);
            acc = __builtin_amdgcn_mfma_f32_16x16x32_bf16(ah, bh, acc, 0, 0, 0);
            acc = __builtin_amdgcn_mfma_f32_16x16x32_bf16(ah, bl, acc, 0, 0, 0);
            acc = __builtin_amdgcn_mfma_f32_16x16x32_bf16(al, bh, acc, 0, 0, 0);
        }
    };

    phaseA(0);

    for (int t = 0; t < T_STEPS; t++){
        // ---- wait for h_t (all WGs' flags >= t) ----
        if (t > 0){
            unsigned tgt = (unsigned)t;
            while (true){
                unsigned f1 = __hip_atomic_load(&flags[lane],      __ATOMIC_RELAXED, __HIP_MEMORY_SCOPE_AGENT);
                unsigned f2 = __hip_atomic_load(&flags[lane + 64], __ATOMIC_RELAXED, __HIP_MEMORY_SCOPE_AGENT);
                if (__all(f1 >= tgt && f2 >= tgt)) break;
                __builtin_amdgcn_s_sleep(1);
            }
            __threadfence();   // acquire: invalidate so h reads are fresh
        }

        // ---- h_t @ U into acc (A frags from packed global h buffer) ----
        const unsigned int* hp = hpk + (size_t)(t & 1) * BATCH * HDIM;
        #pragma unroll
        for (int i = 0; i < KB_HALF; i++){
            int kb = kh * KB_HALF + i;
            const unsigned int* ap = hp + (size_t)row * HDIM + kb * 32 + kgrp * 8;
            uint4 w0 = *reinterpret_cast<const uint4*>(ap);
            uint4 w1 = *reinterpret_cast<const uint4*>(ap + 4);
            unsigned wv[8] = {w0.x, w0.y, w0.z, w0.w, w1.x, w1.y, w1.z, w1.w};
            bf16x8 ah, al;
            #pragma unroll
            for (int j = 0; j < 8; j++){
                ah[j] = (short)(wv[j] & 0xffffu);
                al[j] = (short)(wv[j] >> 16);
            }
            acc = __builtin_amdgcn_mfma_f32_16x16x32_bf16(ah, ufh[i], acc, 0, 0, 0);
            acc = __builtin_amdgcn_mfma_f32_16x16x32_bf16(ah, ufl[i], acc, 0, 0, 0);
            acc = __builtin_amdgcn_mfma_f32_16x16x32_bf16(al, ufh[i], acc, 0, 0, 0);
        }

        // ---- exchange partial z through LDS ----
        #pragma unroll
        for (int r = 0; r < 4; r++)
            z_lds[kh][kgrp * 4 + r + 16 * bt][lane & 15] = acc[r];
        __syncthreads();

        // ---- gates: threads 0..127, one cell (b, hc) each ----
        if (tid < 128){
            float z[4];
            #pragma unroll
            for (int g = 0; g < 4; g++)
                z[g] = z_lds[0][cb][g * 4 + chc] + z_lds[1][cb][g * 4 + chc] + bias_g[g];
            float ig = 1.f / (1.f + __expf(-z[0]));
            float fg = 1.f / (1.f + __expf(-z[1]));
            float gg = tanhf(z[2]);
            float og = 1.f / (1.f + __expf(-z[3]));
            float cn = fg * c_state + ig * gg;
            c_state = cn;
            float hn = og * tanhf(cn);
            int col = wg * 4 + chc;
            out[16384 + ((size_t)t * BATCH + cb) * HDIM + col] = hn;   // hs[t][b][col]
            if (t == T_STEPS - 1){
                out[(size_t)cb * HDIM + col] = hn;                                          // h_T (output 0)
                out[16384 + (size_t)T_STEPS * BATCH * HDIM + (size_t)cb * HDIM + col] = hn; // h_T (output 2)
            }
            unsigned short hi = f2bf(hn);
            unsigned short lo = f2bf(hn - bf2f(hi));
            hpk[(size_t)((t + 1) & 1) * BATCH * HDIM + (size_t)cb * HDIM + col] =
                (unsigned)hi | ((unsigned)lo << 16);
        }
        __syncthreads();   // all stores drained (vmcnt 0 before s_barrier)

        if (tid == 0){
            __threadfence();  // agent release: write back L2 so other XCDs see h
            __hip_atomic_store(&flags[wg], (unsigned)(t + 1), __ATOMIC_RELEASE, __HIP_MEMORY_SCOPE_AGENT);
        }

        // ---- phase A for t+1 (off the inter-WG critical path) ----
        #pragma unroll
        for (int r = 0; r < 4; r++) acc[r] = 0.f;
        if (t + 1 < T_STEPS) phaseA(t + 1);
    }
}

extern "C" void kernel_launch(void* const* d_in, const int* in_sizes, int n_in,
                              void* d_out, int out_size, void* d_ws, size_t ws_size,
                              hipStream_t stream){
    const float* src = (const float*)d_in[0];
    const float* W   = (const float*)d_in[1];
    const float* U   = (const float*)d_in[2];
    const float* b   = (const float*)d_in[3];
    const float* h0  = (const float*)d_in[4];
    const float* c0  = (const float*)d_in[5];
    float* out = (float*)d_out;

    char* ws = (char*)d_ws;
    unsigned int*   flags = (unsigned int*)(ws);
    unsigned int*   hpk   = (unsigned int*)(ws + 1024);
    unsigned short* Wh    = (unsigned short*)(ws + 132096);
    unsigned short* Wl    = Wh + 1048576;
    unsigned short* Uh    = Wl + 1048576;
    unsigned short* Ul    = Uh + 1048576;

    hipMemsetAsync(flags, 0, 512, stream);
    prep_kernel<<<1024, 256, 0, stream>>>(W, U, h0, Wh, Wl, Uh, Ul, hpk);
    lstm_scan<<<NWG, 256, 0, stream>>>(src, b, c0, Wh, Wl, Uh, Ul, hpk, flags, out);
}

// Round 2
// 23233.112 us; speedup vs baseline: 1.8027x; 1.8027x over previous
//
#include <hip/hip_runtime.h>
#include <stdint.h>

#define T_STEPS 2048
#define BATCH 32
#define EDIM 512
#define HDIM 512
#define G4H 2048
#define NWG 128
#define KB_TOTAL 16
#define KB_HALF 8

typedef __attribute__((ext_vector_type(8))) short bf16x8;
typedef __attribute__((ext_vector_type(4))) float f32x4;

// ws layout (bytes):
//   [0,512)          flags: 128 u32 (memset 0 per launch)
//   [1024,132096)    hpk[2][32][512] u32 (bf16 hi | lo<<16), double-buffered h
//   [132096, +2MB)   Wpk_hi   (NWG * 16kb * 64lane * 8 shorts)
//   ... Wpk_lo, Upk_hi, Upk_lo (2MB each)
// total ~8.2 MB

__device__ inline unsigned short f2bf(float x){
    unsigned u = __float_as_uint(x);
    unsigned r = (u + 0x7fffu + ((u >> 16) & 1u)) >> 16;
    return (unsigned short)r;
}
__device__ inline float bf2f(unsigned short s){
    return __uint_as_float(((unsigned)s) << 16);
}

__global__ void prep_kernel(const float* __restrict__ W, const float* __restrict__ U,
                            const float* __restrict__ h0,
                            unsigned short* __restrict__ Wh, unsigned short* __restrict__ Wl,
                            unsigned short* __restrict__ Uh, unsigned short* __restrict__ Ul,
                            unsigned int* __restrict__ hpk0){
    int idx = blockIdx.x * blockDim.x + threadIdx.x;
    int stride = gridDim.x * blockDim.x;
    const int total = 2 * EDIM * G4H;  // 2^21
    for (int i = idx; i < total; i += stride){
        int mat = i >> 20;             // 0=W, 1=U
        int r = i & 1048575;
        int k = r >> 11;               // row in [0,512)
        int col = r & 2047;            // gate column
        float v = (mat ? U : W)[(size_t)k * G4H + col];
        unsigned short hi = f2bf(v);
        unsigned short lo = f2bf(v - bf2f(hi));
        int wg = (col & 511) >> 2;     // h-col block
        int hc = col & 3;
        int g  = col >> 9;             // gate 0..3
        int cl = g * 4 + hc;           // col_local 0..15
        int kb = k >> 5;
        int kgrp = (k >> 3) & 3;
        int j = k & 7;
        int l = kgrp * 16 + cl;        // lane
        size_t dst = (size_t)wg * 8192 + (size_t)kb * 512 + (size_t)l * 8 + j;
        if (mat){ Uh[dst] = hi; Ul[dst] = lo; } else { Wh[dst] = hi; Wl[dst] = lo; }
    }
    for (int i = idx; i < BATCH * HDIM; i += stride){
        float v = h0[i];
        unsigned short hi = f2bf(v);
        unsigned short lo = f2bf(v - bf2f(hi));
        hpk0[i] = (unsigned)hi | ((unsigned)lo << 16);
    }
}

__global__ __launch_bounds__(256, 1) void lstm_scan(
        const float* __restrict__ src, const float* __restrict__ bias,
        const float* __restrict__ c0,
        const unsigned short* __restrict__ Wh, const unsigned short* __restrict__ Wl,
        const unsigned short* __restrict__ Uh, const unsigned short* __restrict__ Ul,
        unsigned int* __restrict__ hpk,        // [2][32][512] packed
        unsigned int* __restrict__ flags,      // [128]
        float* __restrict__ out){
    const int tid  = threadIdx.x;
    const int wg   = blockIdx.x;        // 0..127
    const int lane = tid & 63;
    const int w    = tid >> 6;          // wave 0..3
    const int bt   = w & 1;             // batch tile
    const int kh   = w >> 1;            // k half
    const int row  = (lane & 15) + 16 * bt;   // batch index for A frags
    const int kgrp = lane >> 4;

    __shared__ float z_lds[2][BATCH][17];     // [khalf][b][col_local], padded

    // ---- U fragments: register-resident for this wave's k-half ----
    bf16x8 ufh[KB_HALF], ufl[KB_HALF];
    {
        const uint4* ph = reinterpret_cast<const uint4*>(Uh + (size_t)wg * 8192);
        const uint4* pl = reinterpret_cast<const uint4*>(Ul + (size_t)wg * 8192);
        #pragma unroll
        for (int i = 0; i < KB_HALF; i++){
            int kb = kh * KB_HALF + i;
            uint4 a = ph[kb * 64 + lane];
            uint4 b = pl[kb * 64 + lane];
            ufh[i] = *reinterpret_cast<bf16x8*>(&a);
            ufl[i] = *reinterpret_cast<bf16x8*>(&b);
        }
    }

    // ---- gate-thread state (threads 0..127: one cell each) ----
    const int cb  = tid >> 2;      // batch 0..31
    const int chc = tid & 3;       // h-col within wg
    float c_state = 0.f;
    float bias_g[4] = {0.f, 0.f, 0.f, 0.f};
    if (tid < 128){
        c_state = c0[(size_t)cb * HDIM + wg * 4 + chc];
        #pragma unroll
        for (int g = 0; g < 4; g++) bias_g[g] = bias[g * HDIM + wg * 4 + chc];
    }

    f32x4 acc;
    #pragma unroll
    for (int r = 0; r < 4; r++) acc[r] = 0.f;

    // phase A: x_t @ W (independent of recurrence) into acc
    auto phaseA = [&](int t){
        #pragma unroll
        for (int i = 0; i < KB_HALF; i++){
            int kb = kh * KB_HALF + i;
            const float* xp = src + ((size_t)row * T_STEPS + t) * EDIM + kb * 32 + kgrp * 8;
            float xv[8];
            *reinterpret_cast<float4*>(&xv[0]) = *reinterpret_cast<const float4*>(xp);
            *reinterpret_cast<float4*>(&xv[4]) = *reinterpret_cast<const float4*>(xp + 4);
            bf16x8 ah, al;
            #pragma unroll
            for (int j = 0; j < 8; j++){
                unsigned short hi = f2bf(xv[j]);
                ah[j] = (short)hi;
                al[j] = (short)f2bf(xv[j] - bf2f(hi));
            }
            uint4 bh4 = reinterpret_cast<const uint4*>(Wh + (size_t)wg * 8192)[kb * 64 + lane];
            uint4 bl4 = reinterpret_cast<const uint4*>(Wl + (size_t)wg * 8192)[kb * 64 + lane];
            bf16x8 bh = *reinterpret_cast<bf16x8*>(&bh4);
            bf16x8 bl = *reinterpret_cast<bf16x8*>(&bl4);
            acc = __builtin_amdgcn_mfma_f32_16x16x32_bf16(ah, bh, acc, 0, 0, 0);
            acc = __builtin_amdgcn_mfma_f32_16x16x32_bf16(ah, bl, acc, 0, 0, 0);
            acc = __builtin_amdgcn_mfma_f32_16x16x32_bf16(al, bh, acc, 0, 0, 0);
        }
    };

    phaseA(0);

    for (int t = 0; t < T_STEPS; t++){
        // ---- wait for h_t: wave 0 polls, then releases the block ----
        if (t > 0){
            if (w == 0){
                unsigned tgt = (unsigned)t;
                while (true){
                    unsigned f1 = __hip_atomic_load(&flags[lane],      __ATOMIC_RELAXED, __HIP_MEMORY_SCOPE_AGENT);
                    unsigned f2 = __hip_atomic_load(&flags[lane + 64], __ATOMIC_RELAXED, __HIP_MEMORY_SCOPE_AGENT);
                    if (__all(f1 >= tgt && f2 >= tgt)) break;
                    __builtin_amdgcn_s_sleep(1);
                }
            }
            __syncthreads();
        }

        // ---- h_t @ U into acc (A frags via cache-bypass loads: sc0 sc1 -> L3) ----
        const unsigned int* hp = hpk + (size_t)(t & 1) * BATCH * HDIM;
        unsigned hv[KB_HALF][8];
        #pragma unroll
        for (int i = 0; i < KB_HALF; i++){
            int kb = kh * KB_HALF + i;
            const unsigned int* ap = hp + (size_t)row * HDIM + kb * 32 + kgrp * 8;
            #pragma unroll
            for (int j = 0; j < 8; j++)
                hv[i][j] = __hip_atomic_load(ap + j, __ATOMIC_RELAXED, __HIP_MEMORY_SCOPE_AGENT);
        }
        #pragma unroll
        for (int i = 0; i < KB_HALF; i++){
            bf16x8 ah, al;
            #pragma unroll
            for (int j = 0; j < 8; j++){
                ah[j] = (short)(hv[i][j] & 0xffffu);
                al[j] = (short)(hv[i][j] >> 16);
            }
            acc = __builtin_amdgcn_mfma_f32_16x16x32_bf16(ah, ufh[i], acc, 0, 0, 0);
            acc = __builtin_amdgcn_mfma_f32_16x16x32_bf16(ah, ufl[i], acc, 0, 0, 0);
            acc = __builtin_amdgcn_mfma_f32_16x16x32_bf16(al, ufh[i], acc, 0, 0, 0);
        }

        // ---- exchange partial z through LDS ----
        #pragma unroll
        for (int r = 0; r < 4; r++)
            z_lds[kh][kgrp * 4 + r + 16 * bt][lane & 15] = acc[r];
        __syncthreads();

        // ---- gates: threads 0..127, one cell (b, hc) each ----
        if (tid < 128){
            float z[4];
            #pragma unroll
            for (int g = 0; g < 4; g++)
                z[g] = z_lds[0][cb][g * 4 + chc] + z_lds[1][cb][g * 4 + chc] + bias_g[g];
            float ig = 1.f / (1.f + __expf(-z[0]));
            float fg = 1.f / (1.f + __expf(-z[1]));
            float gg = tanhf(z[2]);
            float og = 1.f / (1.f + __expf(-z[3]));
            float cn = fg * c_state + ig * gg;
            c_state = cn;
            float hn = og * tanhf(cn);
            int col = wg * 4 + chc;
            out[16384 + ((size_t)t * BATCH + cb) * HDIM + col] = hn;   // hs[t][b][col]
            if (t == T_STEPS - 1){
                out[(size_t)cb * HDIM + col] = hn;                                          // h_T (output 0)
                out[16384 + (size_t)T_STEPS * BATCH * HDIM + (size_t)cb * HDIM + col] = hn; // h_T (output 2)
            }
            unsigned short hi = f2bf(hn);
            unsigned short lo = f2bf(hn - bf2f(hi));
            // write-through store (sc0 sc1): lands at L3, visible to all XCDs
            __hip_atomic_store(&hpk[(size_t)((t + 1) & 1) * BATCH * HDIM + (size_t)cb * HDIM + col],
                               (unsigned)hi | ((unsigned)lo << 16),
                               __ATOMIC_RELAXED, __HIP_MEMORY_SCOPE_AGENT);
        }
        // barrier: each wave drains vmcnt(0) before s_barrier, so all hpk
        // write-through stores are at the coherence point before the flag store.
        __syncthreads();

        if (tid == 0){
            __hip_atomic_store(&flags[wg], (unsigned)(t + 1), __ATOMIC_RELAXED, __HIP_MEMORY_SCOPE_AGENT);
        }

        // ---- phase A for t+1 (off the inter-WG critical path) ----
        #pragma unroll
        for (int r = 0; r < 4; r++) acc[r] = 0.f;
        if (t + 1 < T_STEPS) phaseA(t + 1);
    }
}

extern "C" void kernel_launch(void* const* d_in, const int* in_sizes, int n_in,
                              void* d_out, int out_size, void* d_ws, size_t ws_size,
                              hipStream_t stream){
    const float* src = (const float*)d_in[0];
    const float* W   = (const float*)d_in[1];
    const float* U   = (const float*)d_in[2];
    const float* b   = (const float*)d_in[3];
    const float* h0  = (const float*)d_in[4];
    const float* c0  = (const float*)d_in[5];
    float* out = (float*)d_out;

    char* ws = (char*)d_ws;
    unsigned int*   flags = (unsigned int*)(ws);
    unsigned int*   hpk   = (unsigned int*)(ws + 1024);
    unsigned short* Wh    = (unsigned short*)(ws + 132096);
    unsigned short* Wl    = Wh + 1048576;
    unsigned short* Uh    = Wl + 1048576;
    unsigned short* Ul    = Uh + 1048576;

    hipMemsetAsync(flags, 0, 512, stream);
    prep_kernel<<<1024, 256, 0, stream>>>(W, U, h0, Wh, Wl, Uh, Ul, hpk);
    lstm_scan<<<NWG, 256, 0, stream>>>(src, b, c0, Wh, Wl, Uh, Ul, hpk, flags, out);
}